// Round 1
// baseline (415.474 us; speedup 1.0000x reference)
//
#include <hip/hip_runtime.h>
#include <math.h>

#define F_IN 256
#define H1 8
#define C1 128
#define HC1 1024
#define C2 128
#define SLOPE 0.2f

// ---------------- edge sorting (counting sort by dst) ----------------

__global__ void init_deg(int* deg, int n) {
    int i = blockIdx.x * blockDim.x + threadIdx.x;
    if (i < n) deg[i] = 1;  // self-loop
}

__global__ void hist_kernel(const int* __restrict__ dst, int* __restrict__ deg, int E) {
    int i = blockIdx.x * blockDim.x + threadIdx.x;
    if (i < E) atomicAdd(&deg[dst[i]], 1);
}

__global__ void scan_kernel(const int* __restrict__ deg, int* __restrict__ start,
                            int* __restrict__ cursor, int n) {
    __shared__ int buf[1024];
    int carry = 0;
    for (int base = 0; base < n; base += 1024) {
        int i = base + (int)threadIdx.x;
        int v = (i < n) ? deg[i] : 0;
        buf[threadIdx.x] = v;
        __syncthreads();
        for (int offd = 1; offd < 1024; offd <<= 1) {
            int tv = 0;
            if ((int)threadIdx.x >= offd) tv = buf[threadIdx.x - offd];
            __syncthreads();
            if ((int)threadIdx.x >= offd) buf[threadIdx.x] += tv;
            __syncthreads();
        }
        int incl = buf[threadIdx.x];
        if (i < n) { start[i] = carry + incl - v; cursor[i] = carry + incl - v; }
        carry += buf[1023];
        __syncthreads();
    }
    if (threadIdx.x == 0) start[n] = carry;
}

__global__ void scatter_kernel(const int* __restrict__ src, const int* __restrict__ dst,
                               int* __restrict__ cursor, int* __restrict__ ssorted,
                               int E, int N) {
    int i = blockIdx.x * blockDim.x + threadIdx.x;
    if (i < E) {
        int d = dst[i];
        int pos = atomicAdd(&cursor[d], 1);
        ssorted[pos] = src[i];
    } else if (i < E + N) {
        int d = i - E;
        int pos = atomicAdd(&cursor[d], 1);
        ssorted[pos] = d;
    }
}

// ---------------- fp32 tiled SGEMM: C[M,N] = A[M,K] @ B[K,N] ----------------
// BM=64, BN=64, BK=16, 256 threads, 4x4 micro-tile. Requires K%16==0, N%64==0.

template<int BM, int BN, int BK>
__global__ __launch_bounds__(256) void sgemm(const float* __restrict__ A,
                                             const float* __restrict__ B,
                                             float* __restrict__ C,
                                             int M, int N, int K) {
    __shared__ __align__(16) float As[BM][BK + 4];  // 64 x 20 (pad kills stride-16 conflicts)
    __shared__ __align__(16) float Bs[BK][BN];      // 16 x 64
    int t = threadIdx.x;
    int tx = t & 15, ty = t >> 4;
    int row0 = blockIdx.y * BM, col0 = blockIdx.x * BN;

    int a_r = t >> 2;            // 0..63
    int a_k = (t & 3) << 2;      // 0,4,8,12
    int a_row = row0 + a_r;
    int b_k = t >> 4;            // 0..15
    int b_n = (t & 15) << 2;     // 0..60

    float acc[4][4] = {};
    for (int k0 = 0; k0 < K; k0 += BK) {
        float4 av = make_float4(0.f, 0.f, 0.f, 0.f);
        if (a_row < M) av = *(const float4*)(A + (size_t)a_row * K + k0 + a_k);
        *(float4*)(&As[a_r][a_k]) = av;
        float4 bv = *(const float4*)(B + (size_t)(k0 + b_k) * N + col0 + b_n);
        *(float4*)(&Bs[b_k][b_n]) = bv;
        __syncthreads();
#pragma unroll
        for (int kk = 0; kk < BK; kk++) {
            float a0 = As[ty * 4 + 0][kk];
            float a1 = As[ty * 4 + 1][kk];
            float a2 = As[ty * 4 + 2][kk];
            float a3 = As[ty * 4 + 3][kk];
            float4 b = *(const float4*)(&Bs[kk][tx * 4]);
            acc[0][0] += a0 * b.x; acc[0][1] += a0 * b.y; acc[0][2] += a0 * b.z; acc[0][3] += a0 * b.w;
            acc[1][0] += a1 * b.x; acc[1][1] += a1 * b.y; acc[1][2] += a1 * b.z; acc[1][3] += a1 * b.w;
            acc[2][0] += a2 * b.x; acc[2][1] += a2 * b.y; acc[2][2] += a2 * b.z; acc[2][3] += a2 * b.w;
            acc[3][0] += a3 * b.x; acc[3][1] += a3 * b.y; acc[3][2] += a3 * b.z; acc[3][3] += a3 * b.w;
        }
        __syncthreads();
    }
#pragma unroll
    for (int r = 0; r < 4; r++) {
        int gr = row0 + ty * 4 + r;
        if (gr < M) {
            float4 v = make_float4(acc[r][0], acc[r][1], acc[r][2], acc[r][3]);
            *(float4*)(C + (size_t)gr * N + col0 + tx * 4) = v;
        }
    }
}

// ---------------- attention scores ----------------

// layer 1: one wave per (node, head); s_src[n,h] = dot(h[n,h,:], a_src[h,:])
__global__ __launch_bounds__(256) void scores1(const float* __restrict__ h,
                                               const float* __restrict__ a_s,
                                               const float* __restrict__ a_d,
                                               float* __restrict__ ssrc,
                                               float* __restrict__ sdst, int N) {
    int wid = blockIdx.x * 4 + (threadIdx.x >> 6);
    if (wid >= N * H1) return;
    int lane = threadIdx.x & 63;
    int n = wid >> 3, hh = wid & 7;
    const float* hr = h + (size_t)n * HC1 + hh * C1;
    const float* as = a_s + hh * C1;
    const float* ad = a_d + hh * C1;
    float h0 = hr[lane], h1v = hr[lane + 64];
    float vs = h0 * as[lane] + h1v * as[lane + 64];
    float vd = h0 * ad[lane] + h1v * ad[lane + 64];
    for (int off = 32; off; off >>= 1) {
        vs += __shfl_xor(vs, off);
        vd += __shfl_xor(vd, off);
    }
    if (lane == 0) { ssrc[wid] = vs; sdst[wid] = vd; }
}

// layer 2: one wave per node (1 head, C2=128)
__global__ __launch_bounds__(256) void scores2(const float* __restrict__ h,
                                               const float* __restrict__ a_s,
                                               const float* __restrict__ a_d,
                                               float* __restrict__ ssrc,
                                               float* __restrict__ sdst, int N) {
    int n = blockIdx.x * 4 + (threadIdx.x >> 6);
    if (n >= N) return;
    int lane = threadIdx.x & 63;
    const float* hr = h + (size_t)n * C2;
    float h0 = hr[lane], h1v = hr[lane + 64];
    float vs = h0 * a_s[lane] + h1v * a_s[lane + 64];
    float vd = h0 * a_d[lane] + h1v * a_d[lane + 64];
    for (int off = 32; off; off >>= 1) {
        vs += __shfl_xor(vs, off);
        vd += __shfl_xor(vd, off);
    }
    if (lane == 0) { ssrc[n] = vs; sdst[n] = vd; }
}

// ---------------- layer-1 aggregation + bias + ELU ----------------
// one block (256 thr) per dst node; edges [start[d], start[d+1]) sorted by dst.

__device__ __forceinline__ float lrelu(float v) { return v > 0.f ? v : SLOPE * v; }

__global__ __launch_bounds__(256) void agg1(const float* __restrict__ h,
                                            const float* __restrict__ ssrc,
                                            const float* __restrict__ sdst,
                                            const int* __restrict__ start,
                                            const int* __restrict__ ssorted,
                                            const float* __restrict__ b1,
                                            float* __restrict__ out, int N) {
    int d = blockIdx.x;
    int t = threadIdx.x;
    int s0 = start[d];
    int ne = start[d + 1] - s0;
    int eg = t >> 3, hh = t & 7;       // 32 edge-groups x 8 heads

    __shared__ float red[32][8];
    __shared__ float alpha[32][8];
    __shared__ int   srcs[32];

    float sd = sdst[d * H1 + hh];

    // pass 1: per-head max
    float lm = -1e30f;
    for (int e = eg; e < ne; e += 32) {
        float v = lrelu(ssrc[ssorted[s0 + e] * H1 + hh] + sd);
        lm = fmaxf(lm, v);
    }
    red[eg][hh] = lm;
    __syncthreads();
    for (int off = 16; off; off >>= 1) {
        if (eg < off) red[eg][hh] = fmaxf(red[eg][hh], red[eg + off][hh]);
        __syncthreads();
    }
    float m = red[0][hh];
    __syncthreads();

    // pass 2: per-head denom
    float ls = 0.f;
    for (int e = eg; e < ne; e += 32) {
        float v = lrelu(ssrc[ssorted[s0 + e] * H1 + hh] + sd);
        ls += __expf(v - m);
    }
    red[eg][hh] = ls;
    __syncthreads();
    for (int off = 16; off; off >>= 1) {
        if (eg < off) red[eg][hh] += red[eg + off][hh];
        __syncthreads();
    }
    float inv = 1.f / red[0][hh];

    // pass 3: weighted gather-accumulate. thread t owns channels 4t..4t+3,
    // which all live in head (4t)>>7 == t>>5.
    int myh = t >> 5;
    float acc0 = 0.f, acc1 = 0.f, acc2 = 0.f, acc3 = 0.f;
    for (int base = 0; base < ne; base += 32) {
        __syncthreads();
        int e = base + eg;
        if (e < ne) {
            int src = ssorted[s0 + e];
            if (hh == 0) srcs[eg] = src;
            float v = lrelu(ssrc[src * H1 + hh] + sd);
            alpha[eg][hh] = __expf(v - m) * inv;
        }
        __syncthreads();
        int cnt = min(32, ne - base);
        for (int e2 = 0; e2 < cnt; e2++) {
            const float4 hv = ((const float4*)(h + (size_t)srcs[e2] * HC1))[t];
            float al = alpha[e2][myh];
            acc0 += hv.x * al;
            acc1 += hv.y * al;
            acc2 += hv.z * al;
            acc3 += hv.w * al;
        }
    }

    // epilogue: + b1, ELU, store
    float4 bv = ((const float4*)b1)[t];
    float4 ov;
    float v0 = acc0 + bv.x, v1 = acc1 + bv.y, v2 = acc2 + bv.z, v3 = acc3 + bv.w;
    ov.x = v0 > 0.f ? v0 : expm1f(v0);
    ov.y = v1 > 0.f ? v1 : expm1f(v1);
    ov.z = v2 > 0.f ? v2 : expm1f(v2);
    ov.w = v3 > 0.f ? v3 : expm1f(v3);
    ((float4*)(out + (size_t)d * HC1))[t] = ov;
}

// ---------------- layer-2 aggregation + bias ----------------
// one wave per dst node (1 head, 128 channels; 2 per lane)

__global__ __launch_bounds__(256) void agg2(const float* __restrict__ h2,
                                            const float* __restrict__ ssrc,
                                            const float* __restrict__ sdst,
                                            const int* __restrict__ start,
                                            const int* __restrict__ ssorted,
                                            const float* __restrict__ b2,
                                            float* __restrict__ out, int N) {
    int d = blockIdx.x * 4 + (threadIdx.x >> 6);
    if (d >= N) return;
    int lane = threadIdx.x & 63;
    int s0 = start[d];
    int ne = start[d + 1] - s0;
    float sd = sdst[d];

    float lm = -1e30f;
    for (int e = lane; e < ne; e += 64)
        lm = fmaxf(lm, lrelu(ssrc[ssorted[s0 + e]] + sd));
    for (int off = 32; off; off >>= 1) lm = fmaxf(lm, __shfl_xor(lm, off));

    float ls = 0.f;
    for (int e = lane; e < ne; e += 64)
        ls += __expf(lrelu(ssrc[ssorted[s0 + e]] + sd) - lm);
    for (int off = 32; off; off >>= 1) ls += __shfl_xor(ls, off);
    float inv = 1.f / ls;

    float ax = 0.f, ay = 0.f;
    for (int e = 0; e < ne; e++) {
        int src = ssorted[s0 + e];
        float a = __expf(lrelu(ssrc[src] + sd) - lm) * inv;
        float2 hv = ((const float2*)(h2 + (size_t)src * C2))[lane];
        ax += hv.x * a;
        ay += hv.y * a;
    }
    float2 ov;
    ov.x = ax + b2[lane * 2];
    ov.y = ay + b2[lane * 2 + 1];
    ((float2*)(out + (size_t)d * C2))[lane] = ov;
}

// ---------------- launch ----------------

extern "C" void kernel_launch(void* const* d_in, const int* in_sizes, int n_in,
                              void* d_out, int out_size, void* d_ws, size_t ws_size,
                              hipStream_t stream) {
    const float* x      = (const float*)d_in[0];
    const int*   ei     = (const int*)d_in[1];
    const float* W1     = (const float*)d_in[2];
    const float* a_src1 = (const float*)d_in[3];
    const float* a_dst1 = (const float*)d_in[4];
    const float* b1     = (const float*)d_in[5];
    const float* W2     = (const float*)d_in[6];
    const float* a_src2 = (const float*)d_in[7];
    const float* a_dst2 = (const float*)d_in[8];
    const float* b2     = (const float*)d_in[9];
    float* out = (float*)d_out;

    int E = in_sizes[1] / 2;
    int N = in_sizes[0] / F_IN;
    const int* esrc = ei;
    const int* edst = ei + E;

    char* ws = (char*)d_ws;
    size_t off = 0;
    auto alloc = [&](size_t bytes) -> char* {
        char* p = ws + off;
        off = (off + bytes + 255) & ~(size_t)255;
        return p;
    };
    float* h1_lin  = (float*)alloc((size_t)N * HC1 * 4);
    float* h1_act  = (float*)alloc((size_t)N * HC1 * 4);
    float* h2_lin  = (float*)alloc((size_t)N * C2 * 4);
    float* ss1     = (float*)alloc((size_t)N * H1 * 4);
    float* sd1     = (float*)alloc((size_t)N * H1 * 4);
    float* ss2     = (float*)alloc((size_t)N * 4);
    float* sd2     = (float*)alloc((size_t)N * 4);
    int*   deg     = (int*)alloc((size_t)N * 4);
    int*   startp  = (int*)alloc((size_t)(N + 1) * 4);
    int*   cursor  = (int*)alloc((size_t)N * 4);
    int*   ssorted = (int*)alloc((size_t)(E + N) * 4);

    // edge sort by destination
    init_deg<<<(N + 255) / 256, 256, 0, stream>>>(deg, N);
    hist_kernel<<<(E + 255) / 256, 256, 0, stream>>>(edst, deg, E);
    scan_kernel<<<1, 1024, 0, stream>>>(deg, startp, cursor, N);
    scatter_kernel<<<(E + N + 255) / 256, 256, 0, stream>>>(esrc, edst, cursor, ssorted, E, N);

    // layer 1
    sgemm<64, 64, 16><<<dim3(HC1 / 64, (N + 63) / 64), 256, 0, stream>>>(x, W1, h1_lin, N, HC1, F_IN);
    scores1<<<(N * H1 + 3) / 4, 256, 0, stream>>>(h1_lin, a_src1, a_dst1, ss1, sd1, N);
    agg1<<<N, 256, 0, stream>>>(h1_lin, ss1, sd1, startp, ssorted, b1, h1_act, N);

    // layer 2
    sgemm<64, 64, 16><<<dim3(C2 / 64, (N + 63) / 64), 256, 0, stream>>>(h1_act, W2, h2_lin, N, C2, HC1);
    scores2<<<(N + 3) / 4, 256, 0, stream>>>(h2_lin, a_src2, a_dst2, ss2, sd2, N);
    agg2<<<(N + 3) / 4, 256, 0, stream>>>(h2_lin, ss2, sd2, startp, ssorted, b2, out, N);
}

// Round 2
// 389.759 us; speedup vs baseline: 1.0660x; 1.0660x over previous
//
#include <hip/hip_runtime.h>
#include <math.h>

#define F_IN 256
#define H1 8
#define C1 128
#define HC1 1024
#define C2 128
#define SLOPE 0.2f

// ---------------- edge sorting (counting sort by dst) ----------------

__global__ void init_deg(int* deg, int n) {
    int i = blockIdx.x * blockDim.x + threadIdx.x;
    if (i < n) deg[i] = 1;  // self-loop
}

__global__ void hist_kernel(const int* __restrict__ dst, int* __restrict__ deg, int E) {
    int i = blockIdx.x * blockDim.x + threadIdx.x;
    if (i < E) atomicAdd(&deg[dst[i]], 1);
}

__global__ void scan_kernel(const int* __restrict__ deg, int* __restrict__ start,
                            int* __restrict__ cursor, int n) {
    __shared__ int buf[1024];
    int carry = 0;
    for (int base = 0; base < n; base += 1024) {
        int i = base + (int)threadIdx.x;
        int v = (i < n) ? deg[i] : 0;
        buf[threadIdx.x] = v;
        __syncthreads();
        for (int offd = 1; offd < 1024; offd <<= 1) {
            int tv = 0;
            if ((int)threadIdx.x >= offd) tv = buf[threadIdx.x - offd];
            __syncthreads();
            if ((int)threadIdx.x >= offd) buf[threadIdx.x] += tv;
            __syncthreads();
        }
        int incl = buf[threadIdx.x];
        if (i < n) { start[i] = carry + incl - v; cursor[i] = carry + incl - v; }
        carry += buf[1023];
        __syncthreads();
    }
    if (threadIdx.x == 0) start[n] = carry;
}

__global__ void scatter_kernel(const int* __restrict__ src, const int* __restrict__ dst,
                               int* __restrict__ cursor, int* __restrict__ ssorted,
                               int E, int N) {
    int i = blockIdx.x * blockDim.x + threadIdx.x;
    if (i < E) {
        int d = dst[i];
        int pos = atomicAdd(&cursor[d], 1);
        ssorted[pos] = src[i];
    } else if (i < E + N) {
        int d = i - E;
        int pos = atomicAdd(&cursor[d], 1);
        ssorted[pos] = d;
    }
}

// ---------------- helpers ----------------

__device__ __forceinline__ float lrelu(float v) { return v > 0.f ? v : SLOPE * v; }

// round-to-nearest-even fp32 -> bf16, pack two into a uint (a=low, b=high)
__device__ __forceinline__ unsigned pack_bf16(float a, float b) {
    unsigned ua = __float_as_uint(a), ub = __float_as_uint(b);
    ua += 0x7fffu + ((ua >> 16) & 1u);
    ub += 0x7fffu + ((ub >> 16) & 1u);
    return (ua >> 16) | (ub & 0xffff0000u);
}

// ---------------- fp32 tiled SGEMM: C[M,N] = A[M,K] @ B[K,N] ----------------
// BM=64, BN=64, BK=16, 256 threads, 4x4 micro-tile. Optionally also writes a
// packed-bf16 copy of C (consumed by the L2-resident gather kernels).

template<int BM, int BN, int BK, bool BF16OUT>
__global__ __launch_bounds__(256) void sgemm(const float* __restrict__ A,
                                             const float* __restrict__ B,
                                             float* __restrict__ C,
                                             unsigned* __restrict__ Cbf,
                                             int M, int N, int K) {
    __shared__ __align__(16) float As[BM][BK + 4];  // pad kills stride-16 conflicts
    __shared__ __align__(16) float Bs[BK][BN];
    int t = threadIdx.x;
    int tx = t & 15, ty = t >> 4;
    int row0 = blockIdx.y * BM, col0 = blockIdx.x * BN;

    int a_r = t >> 2;            // 0..63
    int a_k = (t & 3) << 2;      // 0,4,8,12
    int a_row = row0 + a_r;
    int b_k = t >> 4;            // 0..15
    int b_n = (t & 15) << 2;     // 0..60

    float acc[4][4] = {};
    for (int k0 = 0; k0 < K; k0 += BK) {
        float4 av = make_float4(0.f, 0.f, 0.f, 0.f);
        if (a_row < M) av = *(const float4*)(A + (size_t)a_row * K + k0 + a_k);
        *(float4*)(&As[a_r][a_k]) = av;
        float4 bv = *(const float4*)(B + (size_t)(k0 + b_k) * N + col0 + b_n);
        *(float4*)(&Bs[b_k][b_n]) = bv;
        __syncthreads();
#pragma unroll
        for (int kk = 0; kk < BK; kk++) {
            float a0 = As[ty * 4 + 0][kk];
            float a1 = As[ty * 4 + 1][kk];
            float a2 = As[ty * 4 + 2][kk];
            float a3 = As[ty * 4 + 3][kk];
            float4 b = *(const float4*)(&Bs[kk][tx * 4]);
            acc[0][0] += a0 * b.x; acc[0][1] += a0 * b.y; acc[0][2] += a0 * b.z; acc[0][3] += a0 * b.w;
            acc[1][0] += a1 * b.x; acc[1][1] += a1 * b.y; acc[1][2] += a1 * b.z; acc[1][3] += a1 * b.w;
            acc[2][0] += a2 * b.x; acc[2][1] += a2 * b.y; acc[2][2] += a2 * b.z; acc[2][3] += a2 * b.w;
            acc[3][0] += a3 * b.x; acc[3][1] += a3 * b.y; acc[3][2] += a3 * b.z; acc[3][3] += a3 * b.w;
        }
        __syncthreads();
    }
#pragma unroll
    for (int r = 0; r < 4; r++) {
        int gr = row0 + ty * 4 + r;
        if (gr < M) {
            float4 v = make_float4(acc[r][0], acc[r][1], acc[r][2], acc[r][3]);
            *(float4*)(C + (size_t)gr * N + col0 + tx * 4) = v;
            if (BF16OUT) {
                uint2 p = make_uint2(pack_bf16(v.x, v.y), pack_bf16(v.z, v.w));
                *(uint2*)(Cbf + (size_t)gr * (N >> 1) + ((col0 + tx * 4) >> 1)) = p;
            }
        }
    }
}

// ---------------- attention scores ----------------

__global__ __launch_bounds__(256) void scores1(const float* __restrict__ h,
                                               const float* __restrict__ a_s,
                                               const float* __restrict__ a_d,
                                               float* __restrict__ ssrc,
                                               float* __restrict__ sdst, int N) {
    int wid = blockIdx.x * 4 + (threadIdx.x >> 6);
    if (wid >= N * H1) return;
    int lane = threadIdx.x & 63;
    int n = wid >> 3, hh = wid & 7;
    const float* hr = h + (size_t)n * HC1 + hh * C1;
    const float* as = a_s + hh * C1;
    const float* ad = a_d + hh * C1;
    float h0 = hr[lane], h1v = hr[lane + 64];
    float vs = h0 * as[lane] + h1v * as[lane + 64];
    float vd = h0 * ad[lane] + h1v * ad[lane + 64];
    for (int off = 32; off; off >>= 1) {
        vs += __shfl_xor(vs, off);
        vd += __shfl_xor(vd, off);
    }
    if (lane == 0) { ssrc[wid] = vs; sdst[wid] = vd; }
}

__global__ __launch_bounds__(256) void scores2(const float* __restrict__ h,
                                               const float* __restrict__ a_s,
                                               const float* __restrict__ a_d,
                                               float* __restrict__ ssrc,
                                               float* __restrict__ sdst, int N) {
    int n = blockIdx.x * 4 + (threadIdx.x >> 6);
    if (n >= N) return;
    int lane = threadIdx.x & 63;
    const float* hr = h + (size_t)n * C2;
    float h0 = hr[lane], h1v = hr[lane + 64];
    float vs = h0 * a_s[lane] + h1v * a_s[lane + 64];
    float vd = h0 * a_d[lane] + h1v * a_d[lane + 64];
    for (int off = 32; off; off >>= 1) {
        vs += __shfl_xor(vs, off);
        vd += __shfl_xor(vd, off);
    }
    if (lane == 0) { ssrc[n] = vs; sdst[n] = vd; }
}

// ---------------- aggregation: one wave per (dst, head) ----------------
// H=8: head = blockIdx.x % 8 -> blocks of one head land on one XCD
// (round-robin), so each XCD's L2 only caches its head's 2.56 MB bf16 slice.
// Payload: packed bf16x2, 4 B/lane (64 lanes cover 128 channels).
// (src, alpha) broadcast to the wave via shuffles -> no __syncthreads at all.

template<int H, bool DOELU>
__global__ __launch_bounds__(256) void agg_bf(const unsigned* __restrict__ hbf,
                                              const float* __restrict__ ssrc,
                                              const float* __restrict__ sdst,
                                              const int* __restrict__ start,
                                              const int* __restrict__ ssorted,
                                              const float* __restrict__ bias,
                                              float* __restrict__ out, int N) {
    int hh, grp;
    if (H == 8) { hh = blockIdx.x & 7; grp = blockIdx.x >> 3; }
    else        { hh = 0;              grp = blockIdx.x; }
    int wid = threadIdx.x >> 6, lane = threadIdx.x & 63;
    int d = grp * 4 + wid;
    if (d >= N) return;
    int s0 = start[d];
    int ne = start[d + 1] - s0;
    float sd = sdst[d * H + hh];

    // first-chunk scores cached in registers (ne <= 64 covers ~all nodes)
    int src0 = 0; float v0 = -1e30f;
    if (lane < ne) { src0 = ssorted[s0 + lane]; v0 = lrelu(ssrc[src0 * H + hh] + sd); }
    float m = v0;
    for (int e = lane + 64; e < ne; e += 64)
        m = fmaxf(m, lrelu(ssrc[ssorted[s0 + e] * H + hh] + sd));
    for (int o = 32; o; o >>= 1) m = fmaxf(m, __shfl_xor(m, o));

    float p0 = (lane < ne) ? __expf(v0 - m) : 0.f;
    float ssum = p0;
    for (int e = lane + 64; e < ne; e += 64)
        ssum += __expf(lrelu(ssrc[ssorted[s0 + e] * H + hh] + sd) - m);
    for (int o = 32; o; o >>= 1) ssum += __shfl_xor(ssum, o);
    float inv = 1.f / ssum;

    float acc0 = 0.f, acc1 = 0.f;
    const int rowstride = H * 64;
    for (int base = 0; base < ne; base += 64) {
        int srcr; float al;
        if (base == 0) { srcr = src0; al = p0 * inv; }
        else {
            srcr = 0; al = 0.f;
            int e = base + lane;
            if (e < ne) {
                srcr = ssorted[s0 + e];
                al = __expf(lrelu(ssrc[srcr * H + hh] + sd) - m) * inv;
            }
        }
        int cnt = min(64, ne - base);
        for (int e2 = 0; e2 < cnt; e2++) {
            float a = __shfl(al, e2);
            int sr = __shfl(srcr, e2);
            unsigned u = hbf[(size_t)sr * rowstride + hh * 64 + lane];
            acc0 += a * __uint_as_float(u << 16);
            acc1 += a * __uint_as_float(u & 0xffff0000u);
        }
    }

    float2 bv = ((const float2*)bias)[hh * 64 + lane];
    float r0 = acc0 + bv.x, r1 = acc1 + bv.y;
    if (DOELU) {
        r0 = r0 > 0.f ? r0 : expm1f(r0);
        r1 = r1 > 0.f ? r1 : expm1f(r1);
    }
    ((float2*)out)[(size_t)d * (H * 64) + hh * 64 + lane] = make_float2(r0, r1);
}

// ---------------- launch ----------------

extern "C" void kernel_launch(void* const* d_in, const int* in_sizes, int n_in,
                              void* d_out, int out_size, void* d_ws, size_t ws_size,
                              hipStream_t stream) {
    const float* x      = (const float*)d_in[0];
    const int*   ei     = (const int*)d_in[1];
    const float* W1     = (const float*)d_in[2];
    const float* a_src1 = (const float*)d_in[3];
    const float* a_dst1 = (const float*)d_in[4];
    const float* b1     = (const float*)d_in[5];
    const float* W2     = (const float*)d_in[6];
    const float* a_src2 = (const float*)d_in[7];
    const float* a_dst2 = (const float*)d_in[8];
    const float* b2     = (const float*)d_in[9];
    float* out = (float*)d_out;

    int E = in_sizes[1] / 2;
    int N = in_sizes[0] / F_IN;
    const int* esrc = ei;
    const int* edst = ei + E;

    char* ws = (char*)d_ws;
    size_t off = 0;
    auto alloc = [&](size_t bytes) -> char* {
        char* p = ws + off;
        off = (off + bytes + 255) & ~(size_t)255;
        return p;
    };
    float*    h1_lin  = (float*)alloc((size_t)N * HC1 * 4);
    float*    h1_act  = (float*)alloc((size_t)N * HC1 * 4);
    float*    h2_lin  = (float*)alloc((size_t)N * C2 * 4);
    unsigned* h1_bf   = (unsigned*)alloc((size_t)N * (HC1 / 2) * 4);
    unsigned* h2_bf   = (unsigned*)alloc((size_t)N * (C2 / 2) * 4);
    float*    ss1     = (float*)alloc((size_t)N * H1 * 4);
    float*    sd1     = (float*)alloc((size_t)N * H1 * 4);
    float*    ss2     = (float*)alloc((size_t)N * 4);
    float*    sd2     = (float*)alloc((size_t)N * 4);
    int*      deg     = (int*)alloc((size_t)N * 4);
    int*      startp  = (int*)alloc((size_t)(N + 1) * 4);
    int*      cursor  = (int*)alloc((size_t)N * 4);
    int*      ssorted = (int*)alloc((size_t)(E + N) * 4);

    // edge sort by destination
    init_deg<<<(N + 255) / 256, 256, 0, stream>>>(deg, N);
    hist_kernel<<<(E + 255) / 256, 256, 0, stream>>>(edst, deg, E);
    scan_kernel<<<1, 1024, 0, stream>>>(deg, startp, cursor, N);
    scatter_kernel<<<(E + N + 255) / 256, 256, 0, stream>>>(esrc, edst, cursor, ssorted, E, N);

    // layer 1
    sgemm<64, 64, 16, true><<<dim3(HC1 / 64, (N + 63) / 64), 256, 0, stream>>>(
        x, W1, h1_lin, h1_bf, N, HC1, F_IN);
    scores1<<<(N * H1 + 3) / 4, 256, 0, stream>>>(h1_lin, a_src1, a_dst1, ss1, sd1, N);
    agg_bf<H1, true><<<((N + 3) / 4) * H1, 256, 0, stream>>>(
        h1_bf, ss1, sd1, startp, ssorted, b1, h1_act, N);

    // layer 2
    sgemm<64, 64, 16, true><<<dim3(C2 / 64, (N + 63) / 64), 256, 0, stream>>>(
        h1_act, W2, h2_lin, h2_bf, N, C2, HC1);
    scores2<<<(N + 3) / 4, 256, 0, stream>>>(h2_lin, a_src2, a_dst2, ss2, sd2, N);
    agg_bf<1, false><<<(N + 3) / 4, 256, 0, stream>>>(
        h2_bf, ss2, sd2, startp, ssorted, b2, out, N);
}

// Round 3
// 299.023 us; speedup vs baseline: 1.3894x; 1.3034x over previous
//
#include <hip/hip_runtime.h>
#include <math.h>

#define F_IN 256
#define H1 8
#define C1 128
#define HC1 1024
#define C2 128
#define SLOPE 0.2f

typedef unsigned short u16;
typedef __attribute__((ext_vector_type(8))) short bf16x8;
typedef __attribute__((ext_vector_type(4))) float f32x4;

// ---------------- helpers ----------------

__device__ __forceinline__ float lrelu(float v) { return v > 0.f ? v : SLOPE * v; }

__device__ __forceinline__ unsigned bf16_rne(float x) {
    unsigned u = __float_as_uint(x);
    u += 0x7fffu + ((u >> 16) & 1u);
    return u >> 16;
}

// split a,b into packed-bf16 hi pair and lo pair (lo = exact residual, rounded)
__device__ __forceinline__ void split2(float a, float b, unsigned& hi, unsigned& lo) {
    unsigned ha = bf16_rne(a), hb = bf16_rne(b);
    float fa = __uint_as_float(ha << 16), fb = __uint_as_float(hb << 16);
    hi = ha | (hb << 16);
    lo = bf16_rne(a - fa) | (bf16_rne(b - fb) << 16);
}

__device__ __forceinline__ void gload16(const u16* g, u16* l) {
    __builtin_amdgcn_global_load_lds(
        (const __attribute__((address_space(1))) unsigned*)g,
        (__attribute__((address_space(3))) unsigned*)l, 16, 0, 0);
}

// ---------------- edge sorting (counting sort by dst) ----------------

__global__ void init_deg(int* deg, int n) {
    int i = blockIdx.x * blockDim.x + threadIdx.x;
    if (i < n) deg[i] = 1;  // self-loop
}

__global__ void hist_kernel(const int* __restrict__ dst, int* __restrict__ deg, int E) {
    int i = blockIdx.x * blockDim.x + threadIdx.x;
    if (i < E) atomicAdd(&deg[dst[i]], 1);
}

__global__ void scan_kernel(const int* __restrict__ deg, int* __restrict__ start,
                            int* __restrict__ cursor, int n) {
    __shared__ int buf[1024];
    int carry = 0;
    for (int base = 0; base < n; base += 1024) {
        int i = base + (int)threadIdx.x;
        int v = (i < n) ? deg[i] : 0;
        buf[threadIdx.x] = v;
        __syncthreads();
        for (int offd = 1; offd < 1024; offd <<= 1) {
            int tv = 0;
            if ((int)threadIdx.x >= offd) tv = buf[threadIdx.x - offd];
            __syncthreads();
            if ((int)threadIdx.x >= offd) buf[threadIdx.x] += tv;
            __syncthreads();
        }
        int incl = buf[threadIdx.x];
        if (i < n) { start[i] = carry + incl - v; cursor[i] = carry + incl - v; }
        carry += buf[1023];
        __syncthreads();
    }
    if (threadIdx.x == 0) start[n] = carry;
}

__global__ void scatter_kernel(const int* __restrict__ src, const int* __restrict__ dst,
                               int* __restrict__ cursor, int* __restrict__ ssorted,
                               int E, int N) {
    int i = blockIdx.x * blockDim.x + threadIdx.x;
    if (i < E) {
        int d = dst[i];
        int pos = atomicAdd(&cursor[d], 1);
        ssorted[pos] = src[i];
    } else if (i < E + N) {
        int d = i - E;
        int pos = atomicAdd(&cursor[d], 1);
        ssorted[pos] = d;
    }
}

// ---------------- fp32 -> bf16 hi/lo split (same layout) ----------------

__global__ void split_mat(const float* __restrict__ in, u16* __restrict__ hi,
                          u16* __restrict__ lo, int n) {
    int i = blockIdx.x * blockDim.x + threadIdx.x;
    if (i >= n) return;
    float v = in[i];
    unsigned h = bf16_rne(v);
    hi[i] = (u16)h;
    lo[i] = (u16)bf16_rne(v - __uint_as_float(h << 16));
}

// in [R][C] -> out [C][R] (hi/lo split + transpose, for B^T operands)
__global__ void split_transpose(const float* __restrict__ in, u16* __restrict__ hi,
                                u16* __restrict__ lo, int R, int C) {
    int i = blockIdx.x * blockDim.x + threadIdx.x;
    if (i >= R * C) return;
    int r = i / C, c = i % C;
    float v = in[i];
    unsigned h = bf16_rne(v);
    hi[(size_t)c * R + r] = (u16)h;
    lo[(size_t)c * R + r] = (u16)bf16_rne(v - __uint_as_float(h << 16));
}

// ---------------- split-bf16 MFMA GEMM ----------------
// C[M,N](bf16) = (Ahi+Alo)[M,K] @ (Bhi+Blo)^T[N,K], fp32 accumulate.
// 128x128 block tile, 4 waves of 64x64, BK=32, global_load_lds staging.

__global__ __launch_bounds__(256) void gemm_mfma(const u16* __restrict__ Ahi,
                                                 const u16* __restrict__ Alo,
                                                 const u16* __restrict__ Bhi,
                                                 const u16* __restrict__ Blo,
                                                 u16* __restrict__ Cbf,
                                                 int M, int N, int K) {
    __shared__ u16 lds[16384];  // 4 tiles x [128][32] bf16 = 32 KB
    const int t = threadIdx.x;
    const int rbase = blockIdx.y * 128;
    const int cbase = blockIdx.x * 128;

    const int lane = t & 63;
    const int R0 = (t >> 7) << 6;         // wave row-half
    const int C0 = ((t >> 6) & 1) << 6;   // wave col-half
    const int lrow = lane & 15;
    const int kq = lane >> 4;

    f32x4 acc[4][4] = {};

    for (int k0 = 0; k0 < K; k0 += 32) {
#pragma unroll
        for (int i = 0; i < 2; i++) {
            int c = t + (i << 8);             // chunk 0..511 (row c>>2, 16B piece c&3)
            int row = c >> 2;
            int kc = (c & 3) << 3;
            int ar = min(rbase + row, M - 1);
            int br = cbase + row;             // always < N (N multiple of 128)
            gload16(Ahi + (size_t)ar * K + k0 + kc, &lds[c * 8]);
            gload16(Alo + (size_t)ar * K + k0 + kc, &lds[4096 + c * 8]);
            gload16(Bhi + (size_t)br * K + k0 + kc, &lds[8192 + c * 8]);
            gload16(Blo + (size_t)br * K + k0 + kc, &lds[12288 + c * 8]);
        }
        __syncthreads();

        bf16x8 ah[4], al[4], bh[4], bl[4];
#pragma unroll
        for (int m = 0; m < 4; m++) {
            int off = (R0 + (m << 4) + lrow) * 32 + (kq << 3);
            ah[m] = *(const bf16x8*)&lds[off];
            al[m] = *(const bf16x8*)&lds[4096 + off];
        }
#pragma unroll
        for (int n = 0; n < 4; n++) {
            int off = (C0 + (n << 4) + lrow) * 32 + (kq << 3);
            bh[n] = *(const bf16x8*)&lds[8192 + off];
            bl[n] = *(const bf16x8*)&lds[12288 + off];
        }
#pragma unroll
        for (int m = 0; m < 4; m++)
#pragma unroll
            for (int n = 0; n < 4; n++) {
                acc[m][n] = __builtin_amdgcn_mfma_f32_16x16x32_bf16(ah[m], bh[n], acc[m][n], 0, 0, 0);
                acc[m][n] = __builtin_amdgcn_mfma_f32_16x16x32_bf16(ah[m], bl[n], acc[m][n], 0, 0, 0);
                acc[m][n] = __builtin_amdgcn_mfma_f32_16x16x32_bf16(al[m], bh[n], acc[m][n], 0, 0, 0);
            }
        __syncthreads();
    }

    // epilogue: C/D layout col=lane&15, row=(lane>>4)*4+reg
#pragma unroll
    for (int m = 0; m < 4; m++)
#pragma unroll
        for (int n = 0; n < 4; n++) {
            int col = cbase + C0 + (n << 4) + lrow;
#pragma unroll
            for (int r = 0; r < 4; r++) {
                int row = rbase + R0 + (m << 4) + kq * 4 + r;
                if (row < M) Cbf[(size_t)row * N + col] = (u16)bf16_rne(acc[m][n][r]);
            }
        }
}

// ---------------- attention scores (bf16 h input) ----------------

__global__ __launch_bounds__(256) void scores1_bf(const unsigned* __restrict__ hbf,
                                                  const float* __restrict__ a_s,
                                                  const float* __restrict__ a_d,
                                                  float* __restrict__ ssrc,
                                                  float* __restrict__ sdst, int N) {
    int wid = blockIdx.x * 4 + (threadIdx.x >> 6);
    if (wid >= N * H1) return;
    int lane = threadIdx.x & 63;
    int n = wid >> 3, hh = wid & 7;
    unsigned u = hbf[(size_t)n * 512 + hh * 64 + lane];
    float c0 = __uint_as_float(u << 16);
    float c1 = __uint_as_float(u & 0xffff0000u);
    const float* as = a_s + hh * C1;
    const float* ad = a_d + hh * C1;
    float vs = c0 * as[2 * lane] + c1 * as[2 * lane + 1];
    float vd = c0 * ad[2 * lane] + c1 * ad[2 * lane + 1];
    for (int off = 32; off; off >>= 1) {
        vs += __shfl_xor(vs, off);
        vd += __shfl_xor(vd, off);
    }
    if (lane == 0) { ssrc[wid] = vs; sdst[wid] = vd; }
}

__global__ __launch_bounds__(256) void scores2_bf(const unsigned* __restrict__ hbf,
                                                  const float* __restrict__ a_s,
                                                  const float* __restrict__ a_d,
                                                  float* __restrict__ ssrc,
                                                  float* __restrict__ sdst, int N) {
    int n = blockIdx.x * 4 + (threadIdx.x >> 6);
    if (n >= N) return;
    int lane = threadIdx.x & 63;
    unsigned u = hbf[(size_t)n * 64 + lane];
    float c0 = __uint_as_float(u << 16);
    float c1 = __uint_as_float(u & 0xffff0000u);
    float vs = c0 * a_s[2 * lane] + c1 * a_s[2 * lane + 1];
    float vd = c0 * a_d[2 * lane] + c1 * a_d[2 * lane + 1];
    for (int off = 32; off; off >>= 1) {
        vs += __shfl_xor(vs, off);
        vd += __shfl_xor(vd, off);
    }
    if (lane == 0) { ssrc[n] = vs; sdst[n] = vd; }
}

// ---------------- aggregation: one wave per (dst, head) ----------------
// SPLITOUT: +bias, ELU, emit hi/lo bf16 pairs (feeds GEMM2's A operand)
// else:     +bias, emit fp32 float2 (final output)

template<int H, bool SPLITOUT>
__global__ __launch_bounds__(256) void agg_bf(const unsigned* __restrict__ hbf,
                                              const float* __restrict__ ssrc,
                                              const float* __restrict__ sdst,
                                              const int* __restrict__ start,
                                              const int* __restrict__ ssorted,
                                              const float* __restrict__ bias,
                                              float* __restrict__ out,
                                              unsigned* __restrict__ outHi,
                                              unsigned* __restrict__ outLo, int N) {
    int hh, grp;
    if (H == 8) { hh = blockIdx.x & 7; grp = blockIdx.x >> 3; }
    else        { hh = 0;              grp = blockIdx.x; }
    int wid = threadIdx.x >> 6, lane = threadIdx.x & 63;
    int d = grp * 4 + wid;
    if (d >= N) return;
    int s0 = start[d];
    int ne = start[d + 1] - s0;
    float sd = sdst[d * H + hh];

    int src0 = 0; float v0 = -1e30f;
    if (lane < ne) { src0 = ssorted[s0 + lane]; v0 = lrelu(ssrc[src0 * H + hh] + sd); }
    float m = v0;
    for (int e = lane + 64; e < ne; e += 64)
        m = fmaxf(m, lrelu(ssrc[ssorted[s0 + e] * H + hh] + sd));
    for (int o = 32; o; o >>= 1) m = fmaxf(m, __shfl_xor(m, o));

    float p0 = (lane < ne) ? __expf(v0 - m) : 0.f;
    float ssum = p0;
    for (int e = lane + 64; e < ne; e += 64)
        ssum += __expf(lrelu(ssrc[ssorted[s0 + e] * H + hh] + sd) - m);
    for (int o = 32; o; o >>= 1) ssum += __shfl_xor(ssum, o);
    float inv = 1.f / ssum;

    float acc0 = 0.f, acc1 = 0.f;
    const int rowstride = H * 64;
    for (int base = 0; base < ne; base += 64) {
        int srcr; float al;
        if (base == 0) { srcr = src0; al = p0 * inv; }
        else {
            srcr = 0; al = 0.f;
            int e = base + lane;
            if (e < ne) {
                srcr = ssorted[s0 + e];
                al = __expf(lrelu(ssrc[srcr * H + hh] + sd) - m) * inv;
            }
        }
        int cnt = min(64, ne - base);
        for (int e2 = 0; e2 < cnt; e2++) {
            float a = __shfl(al, e2);
            int sr = __shfl(srcr, e2);
            unsigned u = hbf[(size_t)sr * rowstride + hh * 64 + lane];
            acc0 += a * __uint_as_float(u << 16);
            acc1 += a * __uint_as_float(u & 0xffff0000u);
        }
    }

    float2 bv = ((const float2*)bias)[hh * 64 + lane];
    float r0 = acc0 + bv.x, r1 = acc1 + bv.y;
    size_t idx = (size_t)d * (H * 64) + hh * 64 + lane;
    if (SPLITOUT) {
        r0 = r0 > 0.f ? r0 : expm1f(r0);
        r1 = r1 > 0.f ? r1 : expm1f(r1);
        unsigned hi, lo;
        split2(r0, r1, hi, lo);
        outHi[idx] = hi;
        outLo[idx] = lo;
    } else {
        ((float2*)out)[idx] = make_float2(r0, r1);
    }
}

// ---------------- launch ----------------

extern "C" void kernel_launch(void* const* d_in, const int* in_sizes, int n_in,
                              void* d_out, int out_size, void* d_ws, size_t ws_size,
                              hipStream_t stream) {
    const float* x      = (const float*)d_in[0];
    const int*   ei     = (const int*)d_in[1];
    const float* W1     = (const float*)d_in[2];
    const float* a_src1 = (const float*)d_in[3];
    const float* a_dst1 = (const float*)d_in[4];
    const float* b1     = (const float*)d_in[5];
    const float* W2     = (const float*)d_in[6];
    const float* a_src2 = (const float*)d_in[7];
    const float* a_dst2 = (const float*)d_in[8];
    const float* b2     = (const float*)d_in[9];
    float* out = (float*)d_out;

    int E = in_sizes[1] / 2;
    int N = in_sizes[0] / F_IN;
    const int* esrc = ei;
    const int* edst = ei + E;

    char* ws = (char*)d_ws;
    size_t off = 0;
    auto alloc = [&](size_t bytes) -> char* {
        char* p = ws + off;
        off = (off + bytes + 255) & ~(size_t)255;
        return p;
    };
    u16* x_hi    = (u16*)alloc((size_t)N * F_IN * 2);
    u16* x_lo    = (u16*)alloc((size_t)N * F_IN * 2);
    u16* W1t_hi  = (u16*)alloc((size_t)F_IN * HC1 * 2);
    u16* W1t_lo  = (u16*)alloc((size_t)F_IN * HC1 * 2);
    u16* W2t_hi  = (u16*)alloc((size_t)HC1 * C2 * 2);
    u16* W2t_lo  = (u16*)alloc((size_t)HC1 * C2 * 2);
    u16* h1_bf   = (u16*)alloc((size_t)N * HC1 * 2);     // x@W1, bf16
    u16* h1a_hi  = (u16*)alloc((size_t)N * HC1 * 2);     // elu(agg1), hi
    u16* h1a_lo  = (u16*)alloc((size_t)N * HC1 * 2);     // elu(agg1), lo
    u16* h2_bf   = (u16*)alloc((size_t)N * C2 * 2);      // h1a@W2, bf16
    float* ss1   = (float*)alloc((size_t)N * H1 * 4);
    float* sd1   = (float*)alloc((size_t)N * H1 * 4);
    float* ss2   = (float*)alloc((size_t)N * 4);
    float* sd2   = (float*)alloc((size_t)N * 4);
    int* deg     = (int*)alloc((size_t)N * 4);
    int* startp  = (int*)alloc((size_t)(N + 1) * 4);
    int* cursor  = (int*)alloc((size_t)N * 4);
    int* ssorted = (int*)alloc((size_t)(E + N) * 4);

    // edge sort by destination
    init_deg<<<(N + 255) / 256, 256, 0, stream>>>(deg, N);
    hist_kernel<<<(E + 255) / 256, 256, 0, stream>>>(edst, deg, E);
    scan_kernel<<<1, 1024, 0, stream>>>(deg, startp, cursor, N);
    scatter_kernel<<<(E + N + 255) / 256, 256, 0, stream>>>(esrc, edst, cursor, ssorted, E, N);

    // operand splits
    split_mat<<<(N * F_IN + 255) / 256, 256, 0, stream>>>(x, x_hi, x_lo, N * F_IN);
    split_transpose<<<(F_IN * HC1 + 255) / 256, 256, 0, stream>>>(W1, W1t_hi, W1t_lo, F_IN, HC1);
    split_transpose<<<(HC1 * C2 + 255) / 256, 256, 0, stream>>>(W2, W2t_hi, W2t_lo, HC1, C2);

    // layer 1
    gemm_mfma<<<dim3(HC1 / 128, (N + 127) / 128), 256, 0, stream>>>(
        x_hi, x_lo, W1t_hi, W1t_lo, h1_bf, N, HC1, F_IN);
    scores1_bf<<<(N * H1 + 3) / 4, 256, 0, stream>>>(
        (const unsigned*)h1_bf, a_src1, a_dst1, ss1, sd1, N);
    agg_bf<H1, true><<<((N + 3) / 4) * H1, 256, 0, stream>>>(
        (const unsigned*)h1_bf, ss1, sd1, startp, ssorted, b1,
        nullptr, (unsigned*)h1a_hi, (unsigned*)h1a_lo, N);

    // layer 2
    gemm_mfma<<<dim3(C2 / 128, (N + 127) / 128), 256, 0, stream>>>(
        h1a_hi, h1a_lo, W2t_hi, W2t_lo, h2_bf, N, C2, HC1);
    scores2_bf<<<(N + 3) / 4, 256, 0, stream>>>(
        (const unsigned*)h2_bf, a_src2, a_dst2, ss2, sd2, N);
    agg_bf<1, false><<<(N + 3) / 4, 256, 0, stream>>>(
        (const unsigned*)h2_bf, ss2, sd2, startp, ssorted, b2,
        out, nullptr, nullptr, N);
}

// Round 4
// 257.902 us; speedup vs baseline: 1.6110x; 1.1594x over previous
//
#include <hip/hip_runtime.h>
#include <math.h>

#define F_IN 256
#define H1 8
#define C1 128
#define HC1 1024
#define C2 128
#define SLOPE 0.2f

typedef unsigned short u16;
typedef __attribute__((ext_vector_type(8))) short bf16x8;
typedef __attribute__((ext_vector_type(4))) float f32x4;

// ---------------- helpers ----------------

__device__ __forceinline__ float lrelu(float v) { return v > 0.f ? v : SLOPE * v; }

__device__ __forceinline__ unsigned bf16_rne(float x) {
    unsigned u = __float_as_uint(x);
    u += 0x7fffu + ((u >> 16) & 1u);
    return u >> 16;
}

// split a,b into packed-bf16 hi pair and lo pair (lo = exact residual, rounded)
__device__ __forceinline__ void split2(float a, float b, unsigned& hi, unsigned& lo) {
    unsigned ha = bf16_rne(a), hb = bf16_rne(b);
    float fa = __uint_as_float(ha << 16), fb = __uint_as_float(hb << 16);
    hi = ha | (hb << 16);
    lo = bf16_rne(a - fa) | (bf16_rne(b - fb) << 16);
}

__device__ __forceinline__ void gload16(const u16* g, u16* l) {
    __builtin_amdgcn_global_load_lds(
        (const __attribute__((address_space(1))) unsigned*)g,
        (__attribute__((address_space(3))) unsigned*)l, 16, 0, 0);
}

// ---------------- edge sorting (counting sort by dst) ----------------

__global__ void init_deg(int* deg, int n) {
    int i = blockIdx.x * blockDim.x + threadIdx.x;
    if (i < n) deg[i] = 1;  // self-loop
}

__global__ void hist_kernel(const int* __restrict__ dst, int* __restrict__ deg, int E) {
    int i = blockIdx.x * blockDim.x + threadIdx.x;
    if (i < E) atomicAdd(&deg[dst[i]], 1);
}

__global__ void scan_kernel(const int* __restrict__ deg, int* __restrict__ start,
                            int* __restrict__ cursor, int n) {
    __shared__ int buf[1024];
    int carry = 0;
    for (int base = 0; base < n; base += 1024) {
        int i = base + (int)threadIdx.x;
        int v = (i < n) ? deg[i] : 0;
        buf[threadIdx.x] = v;
        __syncthreads();
        for (int offd = 1; offd < 1024; offd <<= 1) {
            int tv = 0;
            if ((int)threadIdx.x >= offd) tv = buf[threadIdx.x - offd];
            __syncthreads();
            if ((int)threadIdx.x >= offd) buf[threadIdx.x] += tv;
            __syncthreads();
        }
        int incl = buf[threadIdx.x];
        if (i < n) { start[i] = carry + incl - v; cursor[i] = carry + incl - v; }
        carry += buf[1023];
        __syncthreads();
    }
    if (threadIdx.x == 0) start[n] = carry;
}

__global__ void scatter_kernel(const int* __restrict__ src, const int* __restrict__ dst,
                               int* __restrict__ cursor, int* __restrict__ ssorted,
                               int E, int N) {
    int i = blockIdx.x * blockDim.x + threadIdx.x;
    if (i < E) {
        int d = dst[i];
        int pos = atomicAdd(&cursor[d], 1);
        ssorted[pos] = src[i];
    } else if (i < E + N) {
        int d = i - E;
        int pos = atomicAdd(&cursor[d], 1);
        ssorted[pos] = d;
    }
}

// ---------------- fp32 -> bf16 hi/lo split ----------------

__global__ void split_mat(const float* __restrict__ in, u16* __restrict__ hi,
                          u16* __restrict__ lo, int n) {
    int i = blockIdx.x * blockDim.x + threadIdx.x;
    if (i >= n) return;
    float v = in[i];
    unsigned h = bf16_rne(v);
    hi[i] = (u16)h;
    lo[i] = (u16)bf16_rne(v - __uint_as_float(h << 16));
}

// in [R][C] -> out [C][R]
__global__ void split_transpose(const float* __restrict__ in, u16* __restrict__ hi,
                                u16* __restrict__ lo, int R, int C) {
    int i = blockIdx.x * blockDim.x + threadIdx.x;
    if (i >= R * C) return;
    int r = i / C, c = i % C;
    float v = in[i];
    unsigned h = bf16_rne(v);
    hi[(size_t)c * R + r] = (u16)h;
    lo[(size_t)c * R + r] = (u16)bf16_rne(v - __uint_as_float(h << 16));
}

// ---------------- split-bf16 MFMA GEMM, 128x128 tile ----------------
// C[M,N](bf16) = (Ahi+Alo)[M,K] @ (Bhi+Blo)^T[N,K], fp32 accumulate.

__global__ __launch_bounds__(256) void gemm_mfma(const u16* __restrict__ Ahi,
                                                 const u16* __restrict__ Alo,
                                                 const u16* __restrict__ Bhi,
                                                 const u16* __restrict__ Blo,
                                                 u16* __restrict__ Cbf,
                                                 int M, int N, int K) {
    __shared__ u16 lds[16384];  // 4 tiles x [128][32] bf16 = 32 KB
    const int t = threadIdx.x;
    const int rbase = blockIdx.y * 128;
    const int cbase = blockIdx.x * 128;

    const int lane = t & 63;
    const int R0 = (t >> 7) << 6;
    const int C0 = ((t >> 6) & 1) << 6;
    const int lrow = lane & 15;
    const int kq = lane >> 4;

    f32x4 acc[4][4] = {};

    for (int k0 = 0; k0 < K; k0 += 32) {
#pragma unroll
        for (int i = 0; i < 2; i++) {
            int c = t + (i << 8);
            int row = c >> 2;
            int kc = (c & 3) << 3;
            int ar = min(rbase + row, M - 1);
            int br = cbase + row;
            gload16(Ahi + (size_t)ar * K + k0 + kc, &lds[c * 8]);
            gload16(Alo + (size_t)ar * K + k0 + kc, &lds[4096 + c * 8]);
            gload16(Bhi + (size_t)br * K + k0 + kc, &lds[8192 + c * 8]);
            gload16(Blo + (size_t)br * K + k0 + kc, &lds[12288 + c * 8]);
        }
        __syncthreads();

        bf16x8 ah[4], al[4], bh[4], bl[4];
#pragma unroll
        for (int m = 0; m < 4; m++) {
            int off = (R0 + (m << 4) + lrow) * 32 + (kq << 3);
            ah[m] = *(const bf16x8*)&lds[off];
            al[m] = *(const bf16x8*)&lds[4096 + off];
        }
#pragma unroll
        for (int n = 0; n < 4; n++) {
            int off = (C0 + (n << 4) + lrow) * 32 + (kq << 3);
            bh[n] = *(const bf16x8*)&lds[8192 + off];
            bl[n] = *(const bf16x8*)&lds[12288 + off];
        }
#pragma unroll
        for (int m = 0; m < 4; m++)
#pragma unroll
            for (int n = 0; n < 4; n++) {
                acc[m][n] = __builtin_amdgcn_mfma_f32_16x16x32_bf16(ah[m], bh[n], acc[m][n], 0, 0, 0);
                acc[m][n] = __builtin_amdgcn_mfma_f32_16x16x32_bf16(ah[m], bl[n], acc[m][n], 0, 0, 0);
                acc[m][n] = __builtin_amdgcn_mfma_f32_16x16x32_bf16(al[m], bh[n], acc[m][n], 0, 0, 0);
            }
        __syncthreads();
    }

#pragma unroll
    for (int m = 0; m < 4; m++)
#pragma unroll
        for (int n = 0; n < 4; n++) {
            int col = cbase + C0 + (n << 4) + lrow;
#pragma unroll
            for (int r = 0; r < 4; r++) {
                int row = rbase + R0 + (m << 4) + kq * 4 + r;
                if (row < M) Cbf[(size_t)row * N + col] = (u16)bf16_rne(acc[m][n][r]);
            }
        }
}

// ---------------- split-bf16 MFMA GEMM, 64x64 tile (more blocks; for GEMM2) ----

__global__ __launch_bounds__(256) void gemm_mfma64(const u16* __restrict__ Ahi,
                                                   const u16* __restrict__ Alo,
                                                   const u16* __restrict__ Bhi,
                                                   const u16* __restrict__ Blo,
                                                   u16* __restrict__ Cbf,
                                                   int M, int N, int K) {
    __shared__ u16 lds[8192];  // 4 tiles x [64][32] bf16 = 16 KB
    const int t = threadIdx.x;
    const int rbase = blockIdx.y * 64;
    const int cbase = blockIdx.x * 64;

    const int lane = t & 63;
    const int w = t >> 6;
    const int R0 = (w >> 1) << 5;   // 0 / 32
    const int C0 = (w & 1) << 5;    // 0 / 32
    const int lrow = lane & 15;
    const int kq = lane >> 4;

    f32x4 acc[2][2] = {};

    for (int k0 = 0; k0 < K; k0 += 32) {
        {
            int row = t >> 2;
            int kc = (t & 3) << 3;
            int ar = min(rbase + row, M - 1);
            int br = cbase + row;
            gload16(Ahi + (size_t)ar * K + k0 + kc, &lds[t * 8]);
            gload16(Alo + (size_t)ar * K + k0 + kc, &lds[2048 + t * 8]);
            gload16(Bhi + (size_t)br * K + k0 + kc, &lds[4096 + t * 8]);
            gload16(Blo + (size_t)br * K + k0 + kc, &lds[6144 + t * 8]);
        }
        __syncthreads();

        bf16x8 ah[2], al[2], bh[2], bl[2];
#pragma unroll
        for (int m = 0; m < 2; m++) {
            int off = (R0 + (m << 4) + lrow) * 32 + (kq << 3);
            ah[m] = *(const bf16x8*)&lds[off];
            al[m] = *(const bf16x8*)&lds[2048 + off];
        }
#pragma unroll
        for (int n = 0; n < 2; n++) {
            int off = (C0 + (n << 4) + lrow) * 32 + (kq << 3);
            bh[n] = *(const bf16x8*)&lds[4096 + off];
            bl[n] = *(const bf16x8*)&lds[6144 + off];
        }
#pragma unroll
        for (int m = 0; m < 2; m++)
#pragma unroll
            for (int n = 0; n < 2; n++) {
                acc[m][n] = __builtin_amdgcn_mfma_f32_16x16x32_bf16(ah[m], bh[n], acc[m][n], 0, 0, 0);
                acc[m][n] = __builtin_amdgcn_mfma_f32_16x16x32_bf16(ah[m], bl[n], acc[m][n], 0, 0, 0);
                acc[m][n] = __builtin_amdgcn_mfma_f32_16x16x32_bf16(al[m], bh[n], acc[m][n], 0, 0, 0);
            }
        __syncthreads();
    }

#pragma unroll
    for (int m = 0; m < 2; m++)
#pragma unroll
        for (int n = 0; n < 2; n++) {
            int col = cbase + C0 + (n << 4) + lrow;
#pragma unroll
            for (int r = 0; r < 4; r++) {
                int row = rbase + R0 + (m << 4) + kq * 4 + r;
                if (row < M) Cbf[(size_t)row * N + col] = (u16)bf16_rne(acc[m][n][r]);
            }
        }
}

// ---------------- attention scores (bf16 h input) ----------------

__global__ __launch_bounds__(256) void scores1_bf(const unsigned* __restrict__ hbf,
                                                  const float* __restrict__ a_s,
                                                  const float* __restrict__ a_d,
                                                  float* __restrict__ ssrc,
                                                  float* __restrict__ sdst, int N) {
    int wid = blockIdx.x * 4 + (threadIdx.x >> 6);
    if (wid >= N * H1) return;
    int lane = threadIdx.x & 63;
    int n = wid >> 3, hh = wid & 7;
    unsigned u = hbf[(size_t)n * 512 + hh * 64 + lane];
    float c0 = __uint_as_float(u << 16);
    float c1 = __uint_as_float(u & 0xffff0000u);
    const float* as = a_s + hh * C1;
    const float* ad = a_d + hh * C1;
    float vs = c0 * as[2 * lane] + c1 * as[2 * lane + 1];
    float vd = c0 * ad[2 * lane] + c1 * ad[2 * lane + 1];
    for (int off = 32; off; off >>= 1) {
        vs += __shfl_xor(vs, off);
        vd += __shfl_xor(vd, off);
    }
    if (lane == 0) { ssrc[wid] = vs; sdst[wid] = vd; }
}

__global__ __launch_bounds__(256) void scores2_bf(const unsigned* __restrict__ hbf,
                                                  const float* __restrict__ a_s,
                                                  const float* __restrict__ a_d,
                                                  float* __restrict__ ssrc,
                                                  float* __restrict__ sdst, int N) {
    int n = blockIdx.x * 4 + (threadIdx.x >> 6);
    if (n >= N) return;
    int lane = threadIdx.x & 63;
    unsigned u = hbf[(size_t)n * 64 + lane];
    float c0 = __uint_as_float(u << 16);
    float c1 = __uint_as_float(u & 0xffff0000u);
    float vs = c0 * a_s[2 * lane] + c1 * a_s[2 * lane + 1];
    float vd = c0 * a_d[2 * lane] + c1 * a_d[2 * lane + 1];
    for (int off = 32; off; off >>= 1) {
        vs += __shfl_xor(vs, off);
        vd += __shfl_xor(vd, off);
    }
    if (lane == 0) { ssrc[n] = vs; sdst[n] = vd; }
}

// ---------------- aggregation: one wave per (dst, head) ----------------
// 4 edges per iteration: 16-lane group g handles edge e2+g, each lane loads
// uint4 (8 channels). Cross-group shuffle reduction at the end.
// H=8: head = blockIdx.x % 8 -> one head per XCD (L2-resident 2.56 MB slice).

template<int H, bool SPLITOUT>
__global__ __launch_bounds__(256) void agg_bf(const unsigned* __restrict__ hbf,
                                              const float* __restrict__ ssrc,
                                              const float* __restrict__ sdst,
                                              const int* __restrict__ start,
                                              const int* __restrict__ ssorted,
                                              const float* __restrict__ bias,
                                              float* __restrict__ out,
                                              unsigned* __restrict__ outHi,
                                              unsigned* __restrict__ outLo, int N) {
    int hh, grp;
    if (H == 8) { hh = blockIdx.x & 7; grp = blockIdx.x >> 3; }
    else        { hh = 0;              grp = blockIdx.x; }
    int wid = threadIdx.x >> 6, lane = threadIdx.x & 63;
    int d = grp * 4 + wid;
    if (d >= N) return;
    const int g = lane >> 4, p = lane & 15;
    int s0 = start[d];
    int ne = start[d + 1] - s0;
    float sd = sdst[d * H + hh];

    // lane-based per-edge base pointer (constant over the loop)
    const unsigned* hlane = hbf + hh * 64 + p * 4;
    const int rowstride = H * 64;

    // first-chunk scores cached in registers
    int src0 = 0; float v0 = -1e30f;
    if (lane < ne) { src0 = ssorted[s0 + lane]; v0 = lrelu(ssrc[src0 * H + hh] + sd); }
    float m = v0;
    for (int e = lane + 64; e < ne; e += 64)
        m = fmaxf(m, lrelu(ssrc[ssorted[s0 + e] * H + hh] + sd));
    for (int o = 32; o; o >>= 1) m = fmaxf(m, __shfl_xor(m, o));

    float p0 = (lane < ne) ? __expf(v0 - m) : 0.f;
    float ssum = p0;
    for (int e = lane + 64; e < ne; e += 64)
        ssum += __expf(lrelu(ssrc[ssorted[s0 + e] * H + hh] + sd) - m);
    for (int o = 32; o; o >>= 1) ssum += __shfl_xor(ssum, o);
    float inv = 1.f / ssum;

    float acc[8] = {};
    for (int base = 0; base < ne; base += 64) {
        int srcr; float al;
        if (base == 0) { srcr = src0; al = p0 * inv; }
        else {
            srcr = 0; al = 0.f;
            int e = base + lane;
            if (e < ne) {
                srcr = ssorted[s0 + e];
                al = __expf(lrelu(ssrc[srcr * H + hh] + sd) - m) * inv;
            }
        }
        int cnt = min(64, ne - base);
        // invariant: al == 0 for lanes >= cnt, srcr is a valid index
        for (int e2 = 0; e2 < cnt; e2 += 4) {
            float a = __shfl(al, e2 + g);
            int sr = __shfl(srcr, e2 + g);
            uint4 u = *(const uint4*)(hlane + (size_t)sr * rowstride);
            acc[0] += a * __uint_as_float(u.x << 16);
            acc[1] += a * __uint_as_float(u.x & 0xffff0000u);
            acc[2] += a * __uint_as_float(u.y << 16);
            acc[3] += a * __uint_as_float(u.y & 0xffff0000u);
            acc[4] += a * __uint_as_float(u.z << 16);
            acc[5] += a * __uint_as_float(u.z & 0xffff0000u);
            acc[6] += a * __uint_as_float(u.w << 16);
            acc[7] += a * __uint_as_float(u.w & 0xffff0000u);
        }
    }

    // cross-group reduction: lanes with same p hold the same 8 channels
#pragma unroll
    for (int i = 0; i < 8; i++) {
        acc[i] += __shfl_xor(acc[i], 16);
        acc[i] += __shfl_xor(acc[i], 32);
    }

    // group g writes u32-pair index 4p+g = channels (8p+2g, 8p+2g+1)
    float r0 = g == 0 ? acc[0] : g == 1 ? acc[2] : g == 2 ? acc[4] : acc[6];
    float r1 = g == 0 ? acc[1] : g == 1 ? acc[3] : g == 2 ? acc[5] : acc[7];
    int j = 4 * p + g;
    float2 bv = ((const float2*)bias)[hh * 64 + j];
    r0 += bv.x; r1 += bv.y;
    size_t idx = (size_t)d * (H * 64) + hh * 64 + j;
    if (SPLITOUT) {
        r0 = r0 > 0.f ? r0 : expm1f(r0);
        r1 = r1 > 0.f ? r1 : expm1f(r1);
        unsigned hi, lo;
        split2(r0, r1, hi, lo);
        outHi[idx] = hi;
        outLo[idx] = lo;
    } else {
        ((float2*)out)[idx] = make_float2(r0, r1);
    }
}

// ---------------- launch ----------------

extern "C" void kernel_launch(void* const* d_in, const int* in_sizes, int n_in,
                              void* d_out, int out_size, void* d_ws, size_t ws_size,
                              hipStream_t stream) {
    const float* x      = (const float*)d_in[0];
    const int*   ei     = (const int*)d_in[1];
    const float* W1     = (const float*)d_in[2];
    const float* a_src1 = (const float*)d_in[3];
    const float* a_dst1 = (const float*)d_in[4];
    const float* b1     = (const float*)d_in[5];
    const float* W2     = (const float*)d_in[6];
    const float* a_src2 = (const float*)d_in[7];
    const float* a_dst2 = (const float*)d_in[8];
    const float* b2     = (const float*)d_in[9];
    float* out = (float*)d_out;

    int E = in_sizes[1] / 2;
    int N = in_sizes[0] / F_IN;
    const int* esrc = ei;
    const int* edst = ei + E;

    char* ws = (char*)d_ws;
    size_t off = 0;
    auto alloc = [&](size_t bytes) -> char* {
        char* p = ws + off;
        off = (off + bytes + 255) & ~(size_t)255;
        return p;
    };
    u16* x_hi    = (u16*)alloc((size_t)N * F_IN * 2);
    u16* x_lo    = (u16*)alloc((size_t)N * F_IN * 2);
    u16* W1t_hi  = (u16*)alloc((size_t)F_IN * HC1 * 2);
    u16* W1t_lo  = (u16*)alloc((size_t)F_IN * HC1 * 2);
    u16* W2t_hi  = (u16*)alloc((size_t)HC1 * C2 * 2);
    u16* W2t_lo  = (u16*)alloc((size_t)HC1 * C2 * 2);
    u16* h1_bf   = (u16*)alloc((size_t)N * HC1 * 2);
    u16* h1a_hi  = (u16*)alloc((size_t)N * HC1 * 2);
    u16* h1a_lo  = (u16*)alloc((size_t)N * HC1 * 2);
    u16* h2_bf   = (u16*)alloc((size_t)N * C2 * 2);
    float* ss1   = (float*)alloc((size_t)N * H1 * 4);
    float* sd1   = (float*)alloc((size_t)N * H1 * 4);
    float* ss2   = (float*)alloc((size_t)N * 4);
    float* sd2   = (float*)alloc((size_t)N * 4);
    int* deg     = (int*)alloc((size_t)N * 4);
    int* startp  = (int*)alloc((size_t)(N + 1) * 4);
    int* cursor  = (int*)alloc((size_t)N * 4);
    int* ssorted = (int*)alloc((size_t)(E + N) * 4);

    // edge sort by destination
    init_deg<<<(N + 255) / 256, 256, 0, stream>>>(deg, N);
    hist_kernel<<<(E + 255) / 256, 256, 0, stream>>>(edst, deg, E);
    scan_kernel<<<1, 1024, 0, stream>>>(deg, startp, cursor, N);
    scatter_kernel<<<(E + N + 255) / 256, 256, 0, stream>>>(esrc, edst, cursor, ssorted, E, N);

    // operand splits
    split_mat<<<(N * F_IN + 255) / 256, 256, 0, stream>>>(x, x_hi, x_lo, N * F_IN);
    split_transpose<<<(F_IN * HC1 + 255) / 256, 256, 0, stream>>>(W1, W1t_hi, W1t_lo, F_IN, HC1);
    split_transpose<<<(HC1 * C2 + 255) / 256, 256, 0, stream>>>(W2, W2t_hi, W2t_lo, HC1, C2);

    // layer 1
    gemm_mfma<<<dim3(HC1 / 128, (N + 127) / 128), 256, 0, stream>>>(
        x_hi, x_lo, W1t_hi, W1t_lo, h1_bf, N, HC1, F_IN);
    scores1_bf<<<(N * H1 + 3) / 4, 256, 0, stream>>>(
        (const unsigned*)h1_bf, a_src1, a_dst1, ss1, sd1, N);
    agg_bf<H1, true><<<((N + 3) / 4) * H1, 256, 0, stream>>>(
        (const unsigned*)h1_bf, ss1, sd1, startp, ssorted, b1,
        nullptr, (unsigned*)h1a_hi, (unsigned*)h1a_lo, N);

    // layer 2 (64x64 tiles -> 314 blocks vs 79)
    gemm_mfma64<<<dim3(C2 / 64, (N + 63) / 64), 256, 0, stream>>>(
        h1a_hi, h1a_lo, W2t_hi, W2t_lo, h2_bf, N, C2, HC1);
    scores2_bf<<<(N + 3) / 4, 256, 0, stream>>>(
        (const unsigned*)h2_bf, a_src2, a_dst2, ss2, sd2, N);
    agg_bf<1, false><<<(N + 3) / 4, 256, 0, stream>>>(
        (const unsigned*)h2_bf, ss2, sd2, startp, ssorted, b2,
        out, nullptr, nullptr, N);
}